// Round 7
// baseline (150.043 us; speedup 1.0000x reference)
//
#include <hip/hip_runtime.h>

#define BB 8
#define SS 1024
#define HH 256
#define CC 4
#define NQ 1024  // H*C

typedef unsigned short u16;
typedef unsigned int u32;
typedef __attribute__((ext_vector_type(8))) __bf16 bf16x8;
typedef __attribute__((ext_vector_type(4))) float f32x4;
typedef __attribute__((ext_vector_type(4))) u32 u32x4;
typedef __attribute__((ext_vector_type(4))) u16 u16x4;

__device__ __forceinline__ u16 f2bf(float f) {
    u32 u = __float_as_uint(f);
    u32 r = (u + 0x7FFFu + ((u >> 16) & 1u)) >> 16;
    return (u16)r;
}

__device__ __forceinline__ void gld16(const u16* g, u16* l) {
    __builtin_amdgcn_global_load_lds(
        (const __attribute__((address_space(1))) void*)g,
        (__attribute__((address_space(3))) void*)l, 16, 0, 0);
}

// [rows][64] bf16 tiles, 16B slot ^= (row & 7)
__device__ __forceinline__ bf16x8 ldsfrag(const u16* smem, int row, int c16) {
    const char* p = (const char*)smem + row * 128 + (((c16 ^ (row & 7)) & 7) << 4);
    return *(const bf16x8*)p;
}

#define WAITV(n) asm volatile("s_waitcnt vmcnt(" #n ")" ::: "memory")
#define WAITLG() asm volatile("s_waitcnt lgkmcnt(0)" ::: "memory")

// ---------- prep ----------
__global__ void k0_castx(const float4* __restrict__ x, u16x4* __restrict__ xbf) {
    int i = blockIdx.x * 256 + threadIdx.x;  // 524,288
    float4 v = x[i];
    u16x4 o = {f2bf(v.x), f2bf(v.y), f2bf(v.z), f2bf(v.w)};
    xbf[i] = o;
}

__global__ void k0_transw(const float* __restrict__ Wq, const float* __restrict__ Wk,
                          u16* __restrict__ Wt) {
    __shared__ u16 tl[64][65];
    int nb = blockIdx.x * 64, kb = blockIdx.y * 64;
    int c = threadIdx.x & 63;
#pragma unroll
    for (int r = threadIdx.x >> 6; r < 64; r += 4) {
        int k = kb + r, n = nb + c;
        float v = (n < NQ) ? Wq[k * NQ + n] : Wk[k * NQ + (n - NQ)];
        tl[c][r] = f2bf(v);
    }
    __syncthreads();
#pragma unroll
    for (int r = threadIdx.x >> 6; r < 64; r += 4) {
        Wt[(size_t)(nb + r) * HH + kb + c] = tl[r][c];
    }
}

__global__ void k0_trig(float2* __restrict__ trig) {
    int i = blockIdx.x * 256 + threadIdx.x;  // 32768
    int pos = i >> 7, f = i & 127;
    float freq = __expf(-(float)f * 0.07195578515529633f);
    float ang = (float)pos * freq;
    float s, c;
    sincosf(ang, &s, &c);
    trig[i] = make_float2(c, s);
}

// ---------- staging: [128][64] chunk, 512 thr ----------
#define STAGE2(dst, srcbase, roff, kc)                                          \
    _Pragma("unroll") for (int i_ = 0; i_ < 2; ++i_) {                          \
        int r_ = ww * 16 + i_ * 8 + (l >> 3);                                   \
        int c16_ = (l & 7) ^ (r_ & 7);                                          \
        gld16((srcbase) + (size_t)((roff) + r_) * HH + (kc) * 64 + c16_ * 8,    \
              (dst) + (ww * 16 + i_ * 8) * 64);                                 \
    }
// ---------- staging: [256][64] chunk, 512 thr, 4 gld16/thread ----------
#define STAGE4(dst, srcbase, roff, kc)                                          \
    _Pragma("unroll") for (int i_ = 0; i_ < 4; ++i_) {                          \
        int r_ = i_ * 64 + ww * 8 + (l >> 3);                                   \
        int c16_ = (l & 7) ^ (r_ & 7);                                          \
        gld16((srcbase) + (size_t)((roff) + r_) * HH + (kc) * 64 + c16_ * 8,    \
              (dst) + (i_ * 64 + ww * 8) * 64);                                 \
    }

// ---------- k1: projection + bias + RoPE (128x128, 512 thr, counted-vmcnt dbuf) ----------
__global__ void __launch_bounds__(512, 2) k1_proj(
    const u16* __restrict__ xbf, const u16* __restrict__ Wt,
    const float* __restrict__ bq, const float* __restrict__ bk,
    const int* __restrict__ tok, const float2* __restrict__ trig,
    u16* __restrict__ qpos, u16* __restrict__ qneg,
    u16* __restrict__ kpos, u16* __restrict__ kneg) {
    int h = blockIdx.x;                       // 1024 = 64 m x 16 n
    int logical = (h & 7) * 128 + (h >> 3);   // XCD-chunked
    int m0 = (logical >> 4) * 128, n0 = (logical & 15) * 128;
    int ww = threadIdx.x >> 6, l = threadIdx.x & 63;
    int wr = ww >> 1, wc = ww & 1;

    __shared__ u16 sm[32768];  // 64 KB
    u16* Ab[2] = {sm, sm + 16384};
    u16* Bb[2] = {sm + 8192, sm + 24576};

    f32x4 acc[2][4] = {};
    STAGE2(Ab[0], xbf, m0, 0)
    STAGE2(Bb[0], Wt, n0, 0)
    STAGE2(Ab[1], xbf, m0, 1)
    STAGE2(Bb[1], Wt, n0, 1)
    WAITV(4);
    __builtin_amdgcn_s_barrier();
#pragma unroll
    for (int kc = 0; kc < 4; ++kc) {
        const u16* As = Ab[kc & 1];
        const u16* Bs = Bb[kc & 1];
        __builtin_amdgcn_s_setprio(1);
#pragma unroll
        for (int ks = 0; ks < 2; ++ks) {
            int c16 = (l >> 4) + ks * 4;
            bf16x8 af[2], bfr[4];
#pragma unroll
            for (int mi = 0; mi < 2; ++mi) af[mi] = ldsfrag(As, wr * 32 + mi * 16 + (l & 15), c16);
#pragma unroll
            for (int ns = 0; ns < 4; ++ns) bfr[ns] = ldsfrag(Bs, wc * 64 + ns * 16 + (l & 15), c16);
#pragma unroll
            for (int mi = 0; mi < 2; ++mi)
#pragma unroll
                for (int ns = 0; ns < 4; ++ns)
                    acc[mi][ns] = __builtin_amdgcn_mfma_f32_16x16x32_bf16(af[mi], bfr[ns], acc[mi][ns], 0, 0, 0);
        }
        __builtin_amdgcn_s_setprio(0);
        if (kc < 3) {
            WAITLG();
            __builtin_amdgcn_s_barrier();       // release b[kc&1]
            if (kc < 2) {
                STAGE2(Ab[kc & 1], xbf, m0, kc + 2)
                STAGE2(Bb[kc & 1], Wt, n0, kc + 2)
                WAITV(4);
            } else {
                WAITV(0);
            }
            __builtin_amdgcn_s_barrier();       // b[(kc+1)&1] ready
        }
    }

#pragma unroll
    for (int mi = 0; mi < 2; ++mi)
#pragma unroll
        for (int ns = 0; ns < 4; ++ns) {
            int n = n0 + wc * 64 + ns * 16 + (l & 15);
            bool isq = n < NQ;
            int nc = n & (NQ - 1);
            float bias = isq ? bq[nc] : bk[nc];
            int c = nc >> 8, hh = nc & 255, fi = hh >> 1;
#pragma unroll
            for (int r = 0; r < 4; ++r) {
                int m = m0 + wr * 32 + mi * 16 + (l >> 4) * 4 + r;
                float val = acc[mi][ns][r] + bias;
                float other = __shfl_xor(val, 1);
                int pos = tok[m];
                float2 cs = trig[pos * 128 + fi];
                float rp, rn;
                if ((l & 1) == 0) {
                    rp = val * cs.x - other * cs.y;
                    rn = val * cs.x + other * cs.y;
                } else {
                    rp = other * cs.y + val * cs.x;
                    rn = -other * cs.y + val * cs.x;
                }
                int b = m >> 10, s = m & 1023;
                size_t oidx = ((size_t)((b << 2) | c) * SS + s) * HH + hh;
                if (isq) {
                    qpos[oidx] = f2bf(rp);
                    qneg[oidx] = f2bf(rn);
                } else {
                    kpos[oidx] = f2bf(rp);
                    kneg[oidx] = f2bf(rn);
                }
            }
        }
}

// ---------- k2: 3 disjoint masked passes, 256x256 tiles, 8 waves, 128 KB dbuf ----------
// slot -> (bc, pass, tile); XCD-chunked so each XCD owns 4 consecutive bc (all passes)
__global__ void __launch_bounds__(512, 2) k2_gemm(
    const u16* __restrict__ qpos, const u16* __restrict__ qneg,
    const u16* __restrict__ kpos, const u16* __restrict__ kneg,
    const int* __restrict__ thread_id, float* __restrict__ out) {
    int slot = blockIdx.x;                     // 1536
    int logical = (slot & 7) * 192 + (slot >> 3);
    int bc = logical / 48;
    int rem = logical % 48;
    int pass = rem >> 4;                       // 0: l1, 1: l2(c2), 2: l3(c3)
    int tile = rem & 15;
    int m0 = (tile >> 2) * 256, n0 = (tile & 3) * 256;
    const int* tb = thread_id + (bc >> 2) * SS;

    int ti0 = tb[m0], ti1 = tb[m0 + 255], tj0 = tb[n0], tj1 = tb[n0 + 255];
    bool need;
    if (pass == 0)      need = (ti0 == 0) | (tj0 == 0) | ((ti0 <= tj1) & (tj0 <= ti1));
    else if (pass == 1) need = (ti1 > 0) && (tj1 > (ti0 > 0 ? ti0 : 1));
    else                need = (tj1 > 0) && (ti1 > (tj0 > 0 ? tj0 : 1));
    if (!need) return;

    size_t base = (size_t)bc * (SS * HH);
    const u16* q = (pass == 1 ? qneg : qpos) + base;
    const u16* k = (pass == 2 ? kneg : kpos) + base;
    float* ob = out + (size_t)bc * ((size_t)SS * SS);

    int ww = threadIdx.x >> 6, l = threadIdx.x & 63;
    int wr = ww >> 2, wc = ww & 3;             // wave tile 128x64
    int ar0 = m0 + wr * 128;
    int nb0 = n0 + wc * 64;

    extern __shared__ u16 sm[];                // 128 KB
    u16* Ab[2] = {sm, sm + 32768};
    u16* Bb[2] = {sm + 16384, sm + 49152};

    f32x4 acc[8][4] = {};
    STAGE4(Ab[0], q, m0, 0)
    STAGE4(Bb[0], k, n0, 0)
    STAGE4(Ab[1], q, m0, 1)
    STAGE4(Bb[1], k, n0, 1)
    WAITV(8);
    __builtin_amdgcn_s_barrier();
#pragma unroll
    for (int kc = 0; kc < 4; ++kc) {
        const u16* As = Ab[kc & 1];
        const u16* Bs = Bb[kc & 1];
        __builtin_amdgcn_s_setprio(1);
#pragma unroll
        for (int ks = 0; ks < 2; ++ks) {
            int c16 = (l >> 4) + ks * 4;
            bf16x8 af[8], bfr[4];
#pragma unroll
            for (int ns = 0; ns < 4; ++ns) bfr[ns] = ldsfrag(Bs, wc * 64 + ns * 16 + (l & 15), c16);
#pragma unroll
            for (int mi = 0; mi < 8; ++mi) af[mi] = ldsfrag(As, wr * 128 + mi * 16 + (l & 15), c16);
#pragma unroll
            for (int mi = 0; mi < 8; ++mi)
#pragma unroll
                for (int ns = 0; ns < 4; ++ns)
                    acc[mi][ns] = __builtin_amdgcn_mfma_f32_16x16x32_bf16(af[mi], bfr[ns], acc[mi][ns], 0, 0, 0);
        }
        __builtin_amdgcn_s_setprio(0);
        if (kc < 3) {
            WAITLG();
            __builtin_amdgcn_s_barrier();       // release buf[kc&1]
            if (kc < 2) {
                STAGE4(Ab[kc & 1], q, m0, kc + 2)
                STAGE4(Bb[kc & 1], k, n0, kc + 2)
                WAITV(8);
            } else {
                WAITV(0);
            }
            __builtin_amdgcn_s_barrier();       // buf[(kc+1)&1] ready
        }
    }

    // disjoint masked store
    int tjv[4];
#pragma unroll
    for (int ns = 0; ns < 4; ++ns) tjv[ns] = tb[nb0 + ns * 16 + (l & 15)];
#pragma unroll
    for (int mi = 0; mi < 8; ++mi)
#pragma unroll
        for (int r = 0; r < 4; ++r) {
            int m = ar0 + mi * 16 + (l >> 4) * 4 + r;
            int ti = tb[m];
#pragma unroll
            for (int ns = 0; ns < 4; ++ns) {
                int tj = tjv[ns];
                bool c2 = (ti > 0) & (ti < tj);
                bool c3 = (tj > 0) & (ti > tj);
                bool wm = (pass == 0) ? !(c2 | c3) : ((pass == 1) ? c2 : c3);
                if (wm) {
                    int n = nb0 + ns * 16 + (l & 15);
                    ob[(size_t)m * SS + n] = acc[mi][ns][r];
                }
            }
        }
}

extern "C" void kernel_launch(void* const* d_in, const int* in_sizes, int n_in,
                              void* d_out, int out_size, void* d_ws, size_t ws_size,
                              hipStream_t stream) {
    const float* x  = (const float*)d_in[0];
    const float* Wq = (const float*)d_in[1];
    const float* bq = (const float*)d_in[2];
    const float* Wk = (const float*)d_in[3];
    const float* bk = (const float*)d_in[4];
    const int* tok  = (const int*)d_in[5];
    const int* tid  = (const int*)d_in[6];
    float* out = (float*)d_out;

    char* ws = (char*)d_ws;
    const size_t MB = 1u << 20;
    u16* qpos = (u16*)(ws);
    u16* qneg = (u16*)(ws + 16 * MB);
    u16* kpos = (u16*)(ws + 32 * MB);
    u16* kneg = (u16*)(ws + 48 * MB);
    u16* xbf  = (u16*)(ws + 64 * MB);
    u16* Wt   = (u16*)(ws + 68 * MB);
    float2* trig = (float2*)(ws + 69 * MB);

    k0_castx<<<2048, 256, 0, stream>>>((const float4*)x, (u16x4*)xbf);
    dim3 tg(32, 4);
    k0_transw<<<tg, 256, 0, stream>>>(Wq, Wk, Wt);
    k0_trig<<<128, 256, 0, stream>>>(trig);
    k1_proj<<<1024, 512, 0, stream>>>(xbf, Wt, bq, bk, tok, trig, qpos, qneg, kpos, kneg);
    k2_gemm<<<1536, 512, 131072, stream>>>(qpos, qneg, kpos, kneg, tid, out);
}

// Round 8
// 148.403 us; speedup vs baseline: 1.0110x; 1.0110x over previous
//
#include <hip/hip_runtime.h>

#define BB 8
#define SS 1024
#define HH 256
#define CC 4
#define NQ 1024  // H*C

typedef unsigned short u16;
typedef unsigned int u32;
typedef __attribute__((ext_vector_type(8))) __bf16 bf16x8;
typedef __attribute__((ext_vector_type(4))) float f32x4;
typedef __attribute__((ext_vector_type(4))) u32 u32x4;
typedef __attribute__((ext_vector_type(4))) u16 u16x4;

__device__ __forceinline__ u16 f2bf(float f) {
    u32 u = __float_as_uint(f);
    u32 r = (u + 0x7FFFu + ((u >> 16) & 1u)) >> 16;
    return (u16)r;
}

__device__ __forceinline__ void gld16(const u16* g, u16* l) {
    __builtin_amdgcn_global_load_lds(
        (const __attribute__((address_space(1))) void*)g,
        (__attribute__((address_space(3))) void*)l, 16, 0, 0);
}

// [rows][64] bf16 tiles (BK=64), 16B slot ^= (row & 7)
__device__ __forceinline__ bf16x8 ldsfrag(const u16* smem, int row, int c16) {
    const char* p = (const char*)smem + row * 128 + (((c16 ^ (row & 7)) & 7) << 4);
    return *(const bf16x8*)p;
}
// [rows][32] bf16 tiles (BK=32), 16B slot ^= ((row>>1) & 3)
__device__ __forceinline__ bf16x8 ldsfrag32(const u16* smem, int row, int c16) {
    const char* p = (const char*)smem + row * 64 + (((c16 ^ ((row >> 1) & 3)) & 3) << 4);
    return *(const bf16x8*)p;
}

#define WAITV(n) asm volatile("s_waitcnt vmcnt(" #n ")" ::: "memory")
#define WAITLG() asm volatile("s_waitcnt lgkmcnt(0)" ::: "memory")

// ---------- merged prep: castx (2048 blocks) + transw (128) + trig (128) ----------
__global__ void __launch_bounds__(256) k0_prep(
    const float4* __restrict__ x4, u16x4* __restrict__ xbf4,
    const float* __restrict__ Wq, const float* __restrict__ Wk,
    u16* __restrict__ Wt, float2* __restrict__ trig) {
    __shared__ u16 tl[64][65];
    int b = blockIdx.x;
    if (b < 2048) {
        int i = b * 256 + threadIdx.x;      // 524,288 float4
        float4 v = x4[i];
        u16x4 o = {f2bf(v.x), f2bf(v.y), f2bf(v.z), f2bf(v.w)};
        xbf4[i] = o;
    } else if (b < 2176) {
        int idx = b - 2048;                 // 128 = 32 nb x 4 kb
        int nb = (idx & 31) * 64, kb = (idx >> 5) * 64;
        int c = threadIdx.x & 63;
#pragma unroll
        for (int r = threadIdx.x >> 6; r < 64; r += 4) {
            int k = kb + r, n = nb + c;
            float v = (n < NQ) ? Wq[k * NQ + n] : Wk[k * NQ + (n - NQ)];
            tl[c][r] = f2bf(v);
        }
        __syncthreads();
#pragma unroll
        for (int r = threadIdx.x >> 6; r < 64; r += 4) {
            Wt[(size_t)(nb + r) * HH + kb + c] = tl[r][c];
        }
    } else {
        int i = (b - 2176) * 256 + threadIdx.x;  // 32768
        int pos = i >> 7, f = i & 127;
        float freq = __expf(-(float)f * 0.07195578515529633f);
        float ang = (float)pos * freq;
        float s, c;
        sincosf(ang, &s, &c);
        trig[i] = make_float2(c, s);
    }
}

// ---------- k1 staging: [128][64] chunk, 512 thr ----------
#define STAGE2(dst, srcbase, roff, kc)                                          \
    _Pragma("unroll") for (int i_ = 0; i_ < 2; ++i_) {                          \
        int r_ = ww * 16 + i_ * 8 + (l >> 3);                                   \
        int c16_ = (l & 7) ^ (r_ & 7);                                          \
        gld16((srcbase) + (size_t)((roff) + r_) * HH + (kc) * 64 + c16_ * 8,    \
              (dst) + (ww * 16 + i_ * 8) * 64);                                 \
    }

// ---------- k1: projection + bias + RoPE (128x128, 512 thr, counted-vmcnt dbuf) ----------
__global__ void __launch_bounds__(512, 2) k1_proj(
    const u16* __restrict__ xbf, const u16* __restrict__ Wt,
    const float* __restrict__ bq, const float* __restrict__ bk,
    const int* __restrict__ tok, const float2* __restrict__ trig,
    u16* __restrict__ qpos, u16* __restrict__ qneg,
    u16* __restrict__ kpos, u16* __restrict__ kneg) {
    int h = blockIdx.x;                       // 1024 = 64 m x 16 n
    int logical = (h & 7) * 128 + (h >> 3);   // XCD-chunked
    int m0 = (logical >> 4) * 128, n0 = (logical & 15) * 128;
    int ww = threadIdx.x >> 6, l = threadIdx.x & 63;
    int wr = ww >> 1, wc = ww & 1;

    __shared__ u16 sm[32768];  // 64 KB
    u16* Ab[2] = {sm, sm + 16384};
    u16* Bb[2] = {sm + 8192, sm + 24576};

    f32x4 acc[2][4] = {};
    STAGE2(Ab[0], xbf, m0, 0)
    STAGE2(Bb[0], Wt, n0, 0)
    STAGE2(Ab[1], xbf, m0, 1)
    STAGE2(Bb[1], Wt, n0, 1)
    WAITV(4);
    __builtin_amdgcn_s_barrier();
#pragma unroll
    for (int kc = 0; kc < 4; ++kc) {
        const u16* As = Ab[kc & 1];
        const u16* Bs = Bb[kc & 1];
        __builtin_amdgcn_s_setprio(1);
#pragma unroll
        for (int ks = 0; ks < 2; ++ks) {
            int c16 = (l >> 4) + ks * 4;
            bf16x8 af[2], bfr[4];
#pragma unroll
            for (int mi = 0; mi < 2; ++mi) af[mi] = ldsfrag(As, wr * 32 + mi * 16 + (l & 15), c16);
#pragma unroll
            for (int ns = 0; ns < 4; ++ns) bfr[ns] = ldsfrag(Bs, wc * 64 + ns * 16 + (l & 15), c16);
#pragma unroll
            for (int mi = 0; mi < 2; ++mi)
#pragma unroll
                for (int ns = 0; ns < 4; ++ns)
                    acc[mi][ns] = __builtin_amdgcn_mfma_f32_16x16x32_bf16(af[mi], bfr[ns], acc[mi][ns], 0, 0, 0);
        }
        __builtin_amdgcn_s_setprio(0);
        if (kc < 3) {
            WAITLG();
            __builtin_amdgcn_s_barrier();       // release b[kc&1]
            if (kc < 2) {
                STAGE2(Ab[kc & 1], xbf, m0, kc + 2)
                STAGE2(Bb[kc & 1], Wt, n0, kc + 2)
                WAITV(4);
            } else {
                WAITV(0);
            }
            __builtin_amdgcn_s_barrier();       // b[(kc+1)&1] ready
        }
    }

#pragma unroll
    for (int mi = 0; mi < 2; ++mi)
#pragma unroll
        for (int ns = 0; ns < 4; ++ns) {
            int n = n0 + wc * 64 + ns * 16 + (l & 15);
            bool isq = n < NQ;
            int nc = n & (NQ - 1);
            float bias = isq ? bq[nc] : bk[nc];
            int c = nc >> 8, hh = nc & 255, fi = hh >> 1;
#pragma unroll
            for (int r = 0; r < 4; ++r) {
                int m = m0 + wr * 32 + mi * 16 + (l >> 4) * 4 + r;
                float val = acc[mi][ns][r] + bias;
                float other = __shfl_xor(val, 1);
                int pos = tok[m];
                float2 cs = trig[pos * 128 + fi];
                float rp, rn;
                if ((l & 1) == 0) {
                    rp = val * cs.x - other * cs.y;
                    rn = val * cs.x + other * cs.y;
                } else {
                    rp = other * cs.y + val * cs.x;
                    rn = -other * cs.y + val * cs.x;
                }
                int b = m >> 10, s = m & 1023;
                size_t oidx = ((size_t)((b << 2) | c) * SS + s) * HH + hh;
                if (isq) {
                    qpos[oidx] = f2bf(rp);
                    qneg[oidx] = f2bf(rn);
                } else {
                    kpos[oidx] = f2bf(rp);
                    kneg[oidx] = f2bf(rn);
                }
            }
        }
}

// ---------- k2 staging: [128][32] chunk, 256 thr, 2 gld16/thread/panel ----------
#define KSTAGE(dst, srcbase, roff, kc)                                          \
    _Pragma("unroll") for (int i_ = 0; i_ < 2; ++i_) {                          \
        int sid_ = i_ * 256 + (int)threadIdx.x;                                 \
        int r_ = sid_ >> 2;                                                     \
        int sl_ = (sid_ & 3) ^ ((r_ >> 1) & 3);                                 \
        gld16((srcbase) + (size_t)((roff) + r_) * HH + (kc) * 32 + sl_ * 8,     \
              (dst) + i_ * 2048 + ww * 512);                                    \
    }

// ---------- k2: uniform pass-loop GEMM, 128x128 tiles, 4 waves, 32 KB dbuf ----------
// passes: 0 -> l1 on !(c2|c3), 1 -> l2 on c2, 2 -> l3 on c3 (disjoint stores)
__global__ void __launch_bounds__(256, 4) k2_gemm(
    const u16* __restrict__ qpos, const u16* __restrict__ qneg,
    const u16* __restrict__ kpos, const u16* __restrict__ kneg,
    const int* __restrict__ thread_id, float* __restrict__ out) {
    int slot = blockIdx.x;                      // 2048
    int logical = (slot & 7) * 256 + (slot >> 3);  // XCD x: bc 4x..4x+3
    int bc = logical >> 6;
    int tile = logical & 63;
    int m0 = (tile >> 3) * 128, n0 = (tile & 7) * 128;  // n-inner: A reused
    const int* tb = thread_id + (bc >> 2) * SS;
    int ww = threadIdx.x >> 6, l = threadIdx.x & 63;
    int wr = ww >> 1, wc = ww & 1;              // wave tile 64x64
    int ar0 = m0 + wr * 64;
    int nb0 = n0 + wc * 64;

    int ti0 = tb[m0], ti1 = tb[m0 + 127], tj0 = tb[n0], tj1 = tb[n0 + 127];
    bool need0 = (ti0 == 0) | (tj0 == 0) | ((ti0 <= tj1) & (tj0 <= ti1));
    bool need1 = (ti1 > 0) && (tj1 > (ti0 > 0 ? ti0 : 1));
    bool need2 = (tj1 > 0) && (ti1 > (tj0 > 0 ? tj0 : 1));

    size_t base = (size_t)bc * (SS * HH);
    const u16* qp = qpos + base;
    const u16* qn = qneg + base;
    const u16* kp = kpos + base;
    const u16* kn = kneg + base;
    float* ob = out + (size_t)bc * ((size_t)SS * SS);

    __shared__ u16 sm[16384];  // 32 KB: 2 x (A 4096 + B 4096)

    int tjv[4], ti_[4][4];
#pragma unroll
    for (int ns = 0; ns < 4; ++ns) tjv[ns] = tb[nb0 + ns * 16 + (l & 15)];
#pragma unroll
    for (int mi = 0; mi < 4; ++mi)
#pragma unroll
        for (int r = 0; r < 4; ++r) ti_[mi][r] = tb[ar0 + mi * 16 + (l >> 4) * 4 + r];

#pragma unroll 1
    for (int pass = 0; pass < 3; ++pass) {
        bool need = (pass == 0) ? need0 : ((pass == 1) ? need1 : need2);
        if (!need) continue;                   // block-uniform
        const u16* Ap = (pass == 1) ? qn : qp;
        const u16* Bp = (pass == 2) ? kn : kp;

        f32x4 acc[4][4] = {};
        __builtin_amdgcn_s_barrier();          // prior pass fully done with LDS
        KSTAGE(sm, Ap, m0, 0)
        KSTAGE(sm + 4096, Bp, n0, 0)
        KSTAGE(sm + 8192, Ap, m0, 1)
        KSTAGE(sm + 12288, Bp, n0, 1)
        WAITV(4);
        __builtin_amdgcn_s_barrier();
#pragma unroll
        for (int kc = 0; kc < 8; ++kc) {
            const u16* As = sm + (kc & 1) * 8192;
            const u16* Bs = As + 4096;
            int c16 = l >> 4;
            bf16x8 af[4], bfr[4];
            __builtin_amdgcn_s_setprio(1);
#pragma unroll
            for (int mi = 0; mi < 4; ++mi) af[mi] = ldsfrag32(As, wr * 64 + mi * 16 + (l & 15), c16);
#pragma unroll
            for (int ns = 0; ns < 4; ++ns) bfr[ns] = ldsfrag32(Bs, wc * 64 + ns * 16 + (l & 15), c16);
#pragma unroll
            for (int mi = 0; mi < 4; ++mi)
#pragma unroll
                for (int ns = 0; ns < 4; ++ns)
                    acc[mi][ns] = __builtin_amdgcn_mfma_f32_16x16x32_bf16(af[mi], bfr[ns], acc[mi][ns], 0, 0, 0);
            __builtin_amdgcn_s_setprio(0);
            if (kc < 7) {
                WAITLG();
                __builtin_amdgcn_s_barrier();  // release buf[kc&1]
                if (kc < 6) {
                    u16* db = sm + (kc & 1) * 8192;
                    KSTAGE(db, Ap, m0, kc + 2)
                    KSTAGE(db + 4096, Bp, n0, kc + 2)
                    WAITV(4);
                } else {
                    WAITV(0);
                }
                __builtin_amdgcn_s_barrier();  // buf[(kc+1)&1] ready
            }
        }

        // disjoint masked store
#pragma unroll
        for (int mi = 0; mi < 4; ++mi)
#pragma unroll
            for (int r = 0; r < 4; ++r) {
                int m = ar0 + mi * 16 + (l >> 4) * 4 + r;
                int ti = ti_[mi][r];
#pragma unroll
                for (int ns = 0; ns < 4; ++ns) {
                    int tj = tjv[ns];
                    bool c2 = (ti > 0) & (ti < tj);
                    bool c3 = (tj > 0) & (ti > tj);
                    bool wm = (pass == 0) ? !(c2 | c3) : ((pass == 1) ? c2 : c3);
                    if (wm) {
                        int n = nb0 + ns * 16 + (l & 15);
                        ob[(size_t)m * SS + n] = acc[mi][ns][r];
                    }
                }
            }
    }
}

extern "C" void kernel_launch(void* const* d_in, const int* in_sizes, int n_in,
                              void* d_out, int out_size, void* d_ws, size_t ws_size,
                              hipStream_t stream) {
    const float* x  = (const float*)d_in[0];
    const float* Wq = (const float*)d_in[1];
    const float* bq = (const float*)d_in[2];
    const float* Wk = (const float*)d_in[3];
    const float* bk = (const float*)d_in[4];
    const int* tok  = (const int*)d_in[5];
    const int* tid  = (const int*)d_in[6];
    float* out = (float*)d_out;

    char* ws = (char*)d_ws;
    const size_t MB = 1u << 20;
    u16* qpos = (u16*)(ws);
    u16* qneg = (u16*)(ws + 16 * MB);
    u16* kpos = (u16*)(ws + 32 * MB);
    u16* kneg = (u16*)(ws + 48 * MB);
    u16* xbf  = (u16*)(ws + 64 * MB);
    u16* Wt   = (u16*)(ws + 68 * MB);
    float2* trig = (float2*)(ws + 69 * MB);

    k0_prep<<<2304, 256, 0, stream>>>((const float4*)x, (u16x4*)xbf, Wq, Wk, Wt, trig);
    k1_proj<<<1024, 512, 0, stream>>>(xbf, Wt, bq, bk, tok, trig, qpos, qneg, kpos, kneg);
    k2_gemm<<<2048, 256, 0, stream>>>(qpos, qneg, kpos, kneg, tid, out);
}

// Round 9
// 110.233 us; speedup vs baseline: 1.3611x; 1.3463x over previous
//
#include <hip/hip_runtime.h>

#define BB 8
#define SS 1024
#define HH 256
#define CC 4
#define NQ 1024  // H*C

typedef unsigned short u16;
typedef unsigned int u32;
typedef __attribute__((ext_vector_type(8))) __bf16 bf16x8;
typedef __attribute__((ext_vector_type(4))) float f32x4;
typedef __attribute__((ext_vector_type(4))) u32 u32x4;
typedef __attribute__((ext_vector_type(4))) u16 u16x4;

__device__ __forceinline__ u16 f2bf(float f) {
    u32 u = __float_as_uint(f);
    u32 r = (u + 0x7FFFu + ((u >> 16) & 1u)) >> 16;
    return (u16)r;
}

__device__ __forceinline__ void gld16(const u16* g, u16* l) {
    __builtin_amdgcn_global_load_lds(
        (const __attribute__((address_space(1))) void*)g,
        (__attribute__((address_space(3))) void*)l, 16, 0, 0);
}

// BK=64 tiles: [rows][64], 16B slot ^= (row & 7)
__device__ __forceinline__ bf16x8 ldsfrag(const u16* smem, int row, int c16) {
    const char* p = (const char*)smem + row * 128 + (((c16 ^ (row & 7)) & 7) << 4);
    return *(const bf16x8*)p;
}
// BK=32 tiles: [rows][32], 16B slot ^= ((row>>1) & 3)
__device__ __forceinline__ bf16x8 ldsfrag32(const u16* smem, int row, int c16) {
    const char* p = (const char*)smem + row * 64 + (((c16 ^ ((row >> 1) & 3)) & 3) << 4);
    return *(const bf16x8*)p;
}

#define WAITV(n) asm volatile("s_waitcnt vmcnt(" #n ")" ::: "memory")
#define WAITLG() asm volatile("s_waitcnt lgkmcnt(0)" ::: "memory")

// ---------- merged prep: castx (2048 blocks) + transw (128) + trig (128) ----------
__global__ void __launch_bounds__(256) k0_prep(
    const float4* __restrict__ x4, u16x4* __restrict__ xbf4,
    const float* __restrict__ Wq, const float* __restrict__ Wk,
    u16* __restrict__ Wt, float2* __restrict__ trig) {
    __shared__ u16 tl[64][65];
    int b = blockIdx.x;
    if (b < 2048) {
        int i = b * 256 + threadIdx.x;      // 524,288 float4
        float4 v = x4[i];
        u16x4 o = {f2bf(v.x), f2bf(v.y), f2bf(v.z), f2bf(v.w)};
        xbf4[i] = o;
    } else if (b < 2176) {
        int idx = b - 2048;                 // 128 = 32 nb x 4 kb
        int nb = (idx & 31) * 64, kb = (idx >> 5) * 64;
        int c = threadIdx.x & 63;
#pragma unroll
        for (int r = threadIdx.x >> 6; r < 64; r += 4) {
            int k = kb + r, n = nb + c;
            float v = (n < NQ) ? Wq[k * NQ + n] : Wk[k * NQ + (n - NQ)];
            tl[c][r] = f2bf(v);
        }
        __syncthreads();
#pragma unroll
        for (int r = threadIdx.x >> 6; r < 64; r += 4) {
            Wt[(size_t)(nb + r) * HH + kb + c] = tl[r][c];
        }
    } else {
        int i = (b - 2176) * 256 + threadIdx.x;  // 32768
        int pos = i >> 7, f = i & 127;
        float freq = __expf(-(float)f * 0.07195578515529633f);
        float ang = (float)pos * freq;
        float s, c;
        sincosf(ang, &s, &c);
        trig[i] = make_float2(c, s);
    }
}

// ---------- staging ----------
// BK=64 chunk [128][64], 512 thr, 2 gld16/thread, source-preswizzled
#define STAGE2(dst, srcbase, roff, kc)                                          \
    _Pragma("unroll") for (int i_ = 0; i_ < 2; ++i_) {                          \
        int r_ = ww * 16 + i_ * 8 + (l >> 3);                                   \
        int c16_ = (l & 7) ^ (r_ & 7);                                          \
        gld16((srcbase) + (size_t)((roff) + r_) * HH + (kc) * 64 + c16_ * 8,    \
              (dst) + (ww * 16 + i_ * 8) * 64);                                 \
    }
// BK=32 chunk [128][32], 512 thr, 1 gld16/thread
#define STAGE32(dst, srcbase, roff, kc) do {                                    \
        int r_ = (threadIdx.x >> 2);                                            \
        int sl_ = (threadIdx.x & 3) ^ ((r_ >> 1) & 3);                          \
        gld16((srcbase) + (size_t)((roff) + r_) * HH + (kc) * 32 + sl_ * 8,     \
              (dst) + ww * 512);                                                \
    } while (0)

// ---------- k1: projection + bias + RoPE (128x128, 512 thr, counted-vmcnt dbuf) ----------
__global__ void __launch_bounds__(512, 2) k1_proj(
    const u16* __restrict__ xbf, const u16* __restrict__ Wt,
    const float* __restrict__ bq, const float* __restrict__ bk,
    const int* __restrict__ tok, const float2* __restrict__ trig,
    u16* __restrict__ qpos, u16* __restrict__ qneg,
    u16* __restrict__ kpos, u16* __restrict__ kneg) {
    int h = blockIdx.x;                       // 1024 = 64 m x 16 n
    int logical = (h & 7) * 128 + (h >> 3);   // XCD-chunked
    int m0 = (logical >> 4) * 128, n0 = (logical & 15) * 128;
    int ww = threadIdx.x >> 6, l = threadIdx.x & 63;
    int wr = ww >> 1, wc = ww & 1;

    __shared__ u16 sm[32768];  // 64 KB
    u16* Ab[2] = {sm, sm + 16384};
    u16* Bb[2] = {sm + 8192, sm + 24576};

    f32x4 acc[2][4] = {};
    STAGE2(Ab[0], xbf, m0, 0)
    STAGE2(Bb[0], Wt, n0, 0)
    STAGE2(Ab[1], xbf, m0, 1)
    STAGE2(Bb[1], Wt, n0, 1)
    WAITV(4);
    __builtin_amdgcn_s_barrier();
#pragma unroll
    for (int kc = 0; kc < 4; ++kc) {
        const u16* As = Ab[kc & 1];
        const u16* Bs = Bb[kc & 1];
        __builtin_amdgcn_s_setprio(1);
#pragma unroll
        for (int ks = 0; ks < 2; ++ks) {
            int c16 = (l >> 4) + ks * 4;
            bf16x8 af[2], bfr[4];
#pragma unroll
            for (int mi = 0; mi < 2; ++mi) af[mi] = ldsfrag(As, wr * 32 + mi * 16 + (l & 15), c16);
#pragma unroll
            for (int ns = 0; ns < 4; ++ns) bfr[ns] = ldsfrag(Bs, wc * 64 + ns * 16 + (l & 15), c16);
#pragma unroll
            for (int mi = 0; mi < 2; ++mi)
#pragma unroll
                for (int ns = 0; ns < 4; ++ns)
                    acc[mi][ns] = __builtin_amdgcn_mfma_f32_16x16x32_bf16(af[mi], bfr[ns], acc[mi][ns], 0, 0, 0);
        }
        __builtin_amdgcn_s_setprio(0);
        if (kc < 3) {
            WAITLG();
            __builtin_amdgcn_s_barrier();       // release b[kc&1]
            if (kc < 2) {
                STAGE2(Ab[kc & 1], xbf, m0, kc + 2)
                STAGE2(Bb[kc & 1], Wt, n0, kc + 2)
                WAITV(4);
            } else {
                WAITV(0);
            }
            __builtin_amdgcn_s_barrier();       // b[(kc+1)&1] ready
        }
    }

#pragma unroll
    for (int mi = 0; mi < 2; ++mi)
#pragma unroll
        for (int ns = 0; ns < 4; ++ns) {
            int n = n0 + wc * 64 + ns * 16 + (l & 15);
            bool isq = n < NQ;
            int nc = n & (NQ - 1);
            float bias = isq ? bq[nc] : bk[nc];
            int c = nc >> 8, hh = nc & 255, fi = hh >> 1;
#pragma unroll
            for (int r = 0; r < 4; ++r) {
                int m = m0 + wr * 32 + mi * 16 + (l >> 4) * 4 + r;
                float val = acc[mi][ns][r] + bias;
                float other = __shfl_xor(val, 1);
                int pos = tok[m];
                float2 cs = trig[pos * 128 + fi];
                float rp, rn;
                if ((l & 1) == 0) {
                    rp = val * cs.x - other * cs.y;
                    rn = val * cs.x + other * cs.y;
                } else {
                    rp = other * cs.y + val * cs.x;
                    rn = -other * cs.y + val * cs.x;
                }
                int b = m >> 10, s = m & 1023;
                size_t oidx = ((size_t)((b << 2) | c) * SS + s) * HH + hh;
                if (isq) {
                    qpos[oidx] = f2bf(rp);
                    qneg[oidx] = f2bf(rn);
                } else {
                    kpos[oidx] = f2bf(rp);
                    kneg[oidx] = f2bf(rn);
                }
            }
        }
}

// ---------- k2: merged pure+mixed, 128x128, 512 thr, XCD-chunked, counted-vmcnt ----------
// out stores are NON-TEMPORAL: out is never re-read; keep input panels L2-resident.
__global__ void __launch_bounds__(512, 2) k2_gemm(
    const u16* __restrict__ qpos, const u16* __restrict__ qneg,
    const u16* __restrict__ kpos, const u16* __restrict__ kneg,
    const int* __restrict__ thread_id, float* __restrict__ out) {
    int h = blockIdx.x;                        // 2048
    int logical = (h & 7) * 256 + (h >> 3);    // XCD x: bc 4x..4x+3 sequential
    int bc = logical >> 6;
    int t = logical & 63;
    int m0 = (t >> 3) * 128, n0 = (t & 7) * 128;
    const int* tb = thread_id + (bc >> 2) * SS;
    int ww = threadIdx.x >> 6, l = threadIdx.x & 63;
    int wr = ww >> 1, wc = ww & 1;
    int ti0 = tb[m0], ti1 = tb[m0 + 127], tj0 = tb[n0], tj1 = tb[n0 + 127];
    bool pure2 = (ti0 > 0) & (ti1 < tj0);
    bool pure3 = (tj0 > 0) & (ti0 > tj1);
    bool pure1 = (ti1 == 0) | (tj1 == 0) | ((ti0 == ti1) & (tj0 == tj1) & (ti0 == tj0));
    size_t base = (size_t)bc * (SS * HH);
    float* ob = out + (size_t)bc * ((size_t)SS * SS);
    int ar0 = m0 + wr * 32;
    int nb0 = n0 + wc * 64;

    __shared__ u16 sm[32768];  // 64 KB union

    if (pure1 | pure2 | pure3) {
        const u16* q = (pure2 ? qneg : qpos) + base;
        const u16* k = (pure3 ? kneg : kpos) + base;
        u16* Ab[2] = {sm, sm + 16384};
        u16* Bb[2] = {sm + 8192, sm + 24576};

        f32x4 acc[2][4] = {};
        STAGE2(Ab[0], q, m0, 0)
        STAGE2(Bb[0], k, n0, 0)
        STAGE2(Ab[1], q, m0, 1)
        STAGE2(Bb[1], k, n0, 1)
        WAITV(4);
        __builtin_amdgcn_s_barrier();
#pragma unroll
        for (int kc = 0; kc < 4; ++kc) {
            const u16* As = Ab[kc & 1];
            const u16* Bs = Bb[kc & 1];
            __builtin_amdgcn_s_setprio(1);
#pragma unroll
            for (int ks = 0; ks < 2; ++ks) {
                int c16 = (l >> 4) + ks * 4;
                bf16x8 af[2], bfr[4];
#pragma unroll
                for (int mi = 0; mi < 2; ++mi) af[mi] = ldsfrag(As, wr * 32 + mi * 16 + (l & 15), c16);
#pragma unroll
                for (int ns = 0; ns < 4; ++ns) bfr[ns] = ldsfrag(Bs, wc * 64 + ns * 16 + (l & 15), c16);
#pragma unroll
                for (int mi = 0; mi < 2; ++mi)
#pragma unroll
                    for (int ns = 0; ns < 4; ++ns)
                        acc[mi][ns] = __builtin_amdgcn_mfma_f32_16x16x32_bf16(af[mi], bfr[ns], acc[mi][ns], 0, 0, 0);
            }
            __builtin_amdgcn_s_setprio(0);
            if (kc < 3) {
                WAITLG();
                __builtin_amdgcn_s_barrier();
                if (kc < 2) {
                    STAGE2(Ab[kc & 1], q, m0, kc + 2)
                    STAGE2(Bb[kc & 1], k, n0, kc + 2)
                    WAITV(4);
                } else {
                    WAITV(0);
                }
                __builtin_amdgcn_s_barrier();
            }
        }

#pragma unroll
        for (int mi = 0; mi < 2; ++mi)
#pragma unroll
            for (int ns = 0; ns < 4; ++ns)
#pragma unroll
                for (int r = 0; r < 4; ++r) {
                    int m = ar0 + mi * 16 + (l >> 4) * 4 + r;
                    int n = nb0 + ns * 16 + (l & 15);
                    __builtin_nontemporal_store(acc[mi][ns][r], &ob[(size_t)m * SS + n]);
                }
    } else {
        // ---- mixed: BK=32 x 8 chunks, <=4 streams, counted-vmcnt dbuf ----
        const u16* qp = qpos + base;
        const u16* qn = qneg + base;
        const u16* kp = kpos + base;
        const u16* kn = kneg + base;
        u16* bufb[2] = {sm, sm + 16384};

        int bamin = ti0 > 1 ? ti0 : 1;
        int bcmin = tj0 > 1 ? tj0 : 1;
        bool B2 = (ti1 > 0) && (tj1 > bamin);
        bool B3 = (tj1 > 0) && (ti1 > bcmin);

        int fa[2], fb[2], fc[4], fd[4];
#pragma unroll
        for (int mi = 0; mi < 2; ++mi) {
            fa[mi] = tb[ar0 + mi * 16];
            fb[mi] = tb[ar0 + mi * 16 + 15];
        }
#pragma unroll
        for (int ns = 0; ns < 4; ++ns) {
            fc[ns] = tb[nb0 + ns * 16];
            fd[ns] = tb[nb0 + ns * 16 + 15];
        }
        u32 msk1 = 0, msk2 = 0, msk3 = 0;
#pragma unroll
        for (int mi = 0; mi < 2; ++mi)
#pragma unroll
            for (int ns = 0; ns < 4; ++ns) {
                u32 bit = 1u << (mi * 4 + ns);
                if ((fa[mi] == 0) | (fc[ns] == 0) | ((fa[mi] <= fd[ns]) & (fc[ns] <= fb[mi]))) msk1 |= bit;
                int amin = fa[mi] > 1 ? fa[mi] : 1;
                if ((fb[mi] > 0) & (fd[ns] > amin)) msk2 |= bit;
                int cmin = fc[ns] > 1 ? fc[ns] : 1;
                if ((fd[ns] > 0) & (fb[mi] > cmin)) msk3 |= bit;
            }
        msk1 = __builtin_amdgcn_readfirstlane(msk1);
        msk2 = __builtin_amdgcn_readfirstlane(msk2);
        msk3 = __builtin_amdgcn_readfirstlane(msk3);

#define MSTAGE(bi, kc) do {                                \
        STAGE32(bufb[bi], qp, m0, kc);                     \
        if (B2) STAGE32(bufb[bi] + 4096, qn, m0, kc);      \
        STAGE32(bufb[bi] + 8192, kp, n0, kc);              \
        if (B3) STAGE32(bufb[bi] + 12288, kn, n0, kc);     \
    } while (0)
#define WAITN() do {                                       \
        if (B2 & B3) { WAITV(4); }                         \
        else if (B2 | B3) { WAITV(3); }                    \
        else { WAITV(2); }                                 \
    } while (0)

        f32x4 a1[2][4] = {}, a2[2][4] = {}, a3[2][4] = {};
        MSTAGE(0, 0);
        MSTAGE(1, 1);
        WAITN();
        __builtin_amdgcn_s_barrier();
#pragma unroll
        for (int kc = 0; kc < 8; ++kc) {
            const u16* bqp = bufb[kc & 1];
            const u16* bqn = bqp + 4096;
            const u16* bkp = bqp + 8192;
            const u16* bkn = bqp + 12288;
            int c16 = l >> 4;
            bf16x8 qpF[2], qnF[2], kpF[4], knF[4];
            __builtin_amdgcn_s_setprio(1);
#pragma unroll
            for (int mi = 0; mi < 2; ++mi) {
                int rr = wr * 32 + mi * 16 + (l & 15);
                qpF[mi] = ldsfrag32(bqp, rr, c16);
                if (msk2) qnF[mi] = ldsfrag32(bqn, rr, c16);
            }
#pragma unroll
            for (int ns = 0; ns < 4; ++ns) {
                int rn = wc * 64 + ns * 16 + (l & 15);
                kpF[ns] = ldsfrag32(bkp, rn, c16);
                if (msk3) knF[ns] = ldsfrag32(bkn, rn, c16);
            }
#pragma unroll
            for (int mi = 0; mi < 2; ++mi)
#pragma unroll
                for (int ns = 0; ns < 4; ++ns) {
                    u32 bit = 1u << (mi * 4 + ns);
                    if (msk1 & bit)
                        a1[mi][ns] = __builtin_amdgcn_mfma_f32_16x16x32_bf16(qpF[mi], kpF[ns], a1[mi][ns], 0, 0, 0);
                    if (msk2 & bit)
                        a2[mi][ns] = __builtin_amdgcn_mfma_f32_16x16x32_bf16(qnF[mi], kpF[ns], a2[mi][ns], 0, 0, 0);
                    if (msk3 & bit)
                        a3[mi][ns] = __builtin_amdgcn_mfma_f32_16x16x32_bf16(qpF[mi], knF[ns], a3[mi][ns], 0, 0, 0);
                }
            __builtin_amdgcn_s_setprio(0);
            if (kc < 7) {
                WAITLG();
                __builtin_amdgcn_s_barrier();   // release buf[kc&1]
                if (kc < 6) {
                    MSTAGE(kc & 1, kc + 2);
                    WAITN();
                } else {
                    WAITV(0);
                }
                __builtin_amdgcn_s_barrier();   // buf[(kc+1)&1] ready
            }
        }
#undef MSTAGE
#undef WAITN

        int tj[4], ti_[2][4];
#pragma unroll
        for (int ns = 0; ns < 4; ++ns) tj[ns] = tb[nb0 + ns * 16 + (l & 15)];
#pragma unroll
        for (int mi = 0; mi < 2; ++mi)
#pragma unroll
            for (int r = 0; r < 4; ++r) ti_[mi][r] = tb[ar0 + mi * 16 + (l >> 4) * 4 + r];

#pragma unroll
        for (int mi = 0; mi < 2; ++mi)
#pragma unroll
            for (int ns = 0; ns < 4; ++ns)
#pragma unroll
                for (int r = 0; r < 4; ++r) {
                    int m = ar0 + mi * 16 + (l >> 4) * 4 + r;
                    int n = nb0 + ns * 16 + (l & 15);
                    int ti = ti_[mi][r], tjj = tj[ns];
                    float v = (ti > 0 && ti < tjj) ? a2[mi][ns][r]
                             : ((tjj > 0 && ti > tjj) ? a3[mi][ns][r] : a1[mi][ns][r]);
                    __builtin_nontemporal_store(v, &ob[(size_t)m * SS + n]);
                }
    }
}

extern "C" void kernel_launch(void* const* d_in, const int* in_sizes, int n_in,
                              void* d_out, int out_size, void* d_ws, size_t ws_size,
                              hipStream_t stream) {
    const float* x  = (const float*)d_in[0];
    const float* Wq = (const float*)d_in[1];
    const float* bq = (const float*)d_in[2];
    const float* Wk = (const float*)d_in[3];
    const float* bk = (const float*)d_in[4];
    const int* tok  = (const int*)d_in[5];
    const int* tid  = (const int*)d_in[6];
    float* out = (float*)d_out;

    char* ws = (char*)d_ws;
    const size_t MB = 1u << 20;
    u16* qpos = (u16*)(ws);
    u16* qneg = (u16*)(ws + 16 * MB);
    u16* kpos = (u16*)(ws + 32 * MB);
    u16* kneg = (u16*)(ws + 48 * MB);
    u16* xbf  = (u16*)(ws + 64 * MB);
    u16* Wt   = (u16*)(ws + 68 * MB);
    float2* trig = (float2*)(ws + 69 * MB);

    k0_prep<<<2304, 256, 0, stream>>>((const float4*)x, (u16x4*)xbf, Wq, Wk, Wt, trig);
    k1_proj<<<1024, 512, 0, stream>>>(xbf, Wt, bq, bk, tok, trig, qpos, qneg, kpos, kneg);
    k2_gemm<<<2048, 512, 0, stream>>>(qpos, qneg, kpos, kneg, tid, out);
}